// Round 3
// baseline (19996.178 us; speedup 1.0000x reference)
//
#include <hip/hip_runtime.h>
#include <hip/hip_bf16.h>
#include <math.h>

#define V 10000
#define E 512
#define H 1024
#define T 128
#define B 64
#define NWG 256
#define KC 256   // k-chunk staged in LDS for persistent kernel (64 KB)

typedef __bf16 bf16x8 __attribute__((ext_vector_type(8)));
typedef float f32x4 __attribute__((ext_vector_type(4)));
typedef unsigned short ushort8 __attribute__((ext_vector_type(8)));

// ---------------------------------------------------------------------------
// Split-pack 4 fp32 into truncated-hi bf16 and residual-lo bf16.
// ---------------------------------------------------------------------------
__device__ inline void splitpack(float4 v, uint2& hi, uint2& lo) {
    unsigned u0 = __float_as_uint(v.x), u1 = __float_as_uint(v.y);
    unsigned u2 = __float_as_uint(v.z), u3 = __float_as_uint(v.w);
    hi.x = __builtin_amdgcn_perm(u1, u0, 0x07060302u);
    hi.y = __builtin_amdgcn_perm(u3, u2, 0x07060302u);
    float l0 = v.x - __uint_as_float(u0 & 0xFFFF0000u);
    float l1 = v.y - __uint_as_float(u1 & 0xFFFF0000u);
    float l2 = v.z - __uint_as_float(u2 & 0xFFFF0000u);
    float l3 = v.w - __uint_as_float(u3 & 0xFFFF0000u);
    lo.x = __builtin_amdgcn_perm(__float_as_uint(l1), __float_as_uint(l0), 0x07060302u);
    lo.y = __builtin_amdgcn_perm(__float_as_uint(l3), __float_as_uint(l2), 0x07060302u);
}

// ---------------------------------------------------------------------------
// Split-bf16 MFMA GEMM (as round 2; unchanged)
// ---------------------------------------------------------------------------
__global__ __launch_bounds__(256) void gemm_mfma_split(
    const float* __restrict__ A, const float* __restrict__ W,
    const float* __restrict__ bias, float* __restrict__ C,
    const int* __restrict__ rowidx,
    int M, int N, int K, int lda, int ldb, int ldc, int coff)
{
    __shared__ __align__(16) unsigned short Ah[128 * 40];
    __shared__ __align__(16) unsigned short Al[128 * 40];
    __shared__ __align__(16) unsigned short Bh[128 * 40];
    __shared__ __align__(16) unsigned short Bl[128 * 40];

    const int tid  = threadIdx.x;
    const int lane = tid & 63;
    const int wv   = tid >> 6;
    const int wm   = wv & 1, wn = wv >> 1;
    const int bn = blockIdx.x * 128;
    const int bm = blockIdx.y * 128;

    const float* apt[4];
    const float* bpt[4];
    bool bok[4];
    unsigned lofs[4];
    #pragma unroll
    for (int i = 0; i < 4; ++i) {
        int f4 = i * 256 + tid, r = f4 >> 3, kq = f4 & 7;
        int gm = bm + r;
        int ar = rowidx ? rowidx[gm] : gm;
        apt[i] = A + (size_t)ar * lda + kq * 4;
        int gn = bn + r;
        bok[i] = (gn < N);
        bpt[i] = W + (size_t)(bok[i] ? gn : 0) * ldb + kq * 4;
        lofs[i] = r * 40 + kq * 4;
    }

    f32x4 acc[4][4];
    #pragma unroll
    for (int i = 0; i < 4; ++i)
        #pragma unroll
        for (int j = 0; j < 4; ++j) acc[i][j] = (f32x4){0.f, 0.f, 0.f, 0.f};

    const int la  = lane & 15;
    const int kg8 = (lane >> 4) * 8;

    for (int k0 = 0; k0 < K; k0 += 32) {
        __syncthreads();
        #pragma unroll
        for (int i = 0; i < 4; ++i) {
            float4 va = *(const float4*)(apt[i] + k0);
            uint2 h, l;
            splitpack(va, h, l);
            *(uint2*)&Ah[lofs[i]] = h;
            *(uint2*)&Al[lofs[i]] = l;
            float4 vb = {0.f, 0.f, 0.f, 0.f};
            if (bok[i]) vb = *(const float4*)(bpt[i] + k0);
            splitpack(vb, h, l);
            *(uint2*)&Bh[lofs[i]] = h;
            *(uint2*)&Bl[lofs[i]] = l;
        }
        __syncthreads();

        bf16x8 ah[4], al[4];
        #pragma unroll
        for (int mt = 0; mt < 4; ++mt) {
            int row = (wm * 64 + mt * 16 + la) * 40 + kg8;
            ah[mt] = __builtin_bit_cast(bf16x8, *(const ushort8*)&Ah[row]);
            al[mt] = __builtin_bit_cast(bf16x8, *(const ushort8*)&Al[row]);
        }
        #pragma unroll
        for (int nt = 0; nt < 4; ++nt) {
            int row = (wn * 64 + nt * 16 + la) * 40 + kg8;
            bf16x8 bh = __builtin_bit_cast(bf16x8, *(const ushort8*)&Bh[row]);
            bf16x8 bl = __builtin_bit_cast(bf16x8, *(const ushort8*)&Bl[row]);
            #pragma unroll
            for (int mt = 0; mt < 4; ++mt) {
                acc[mt][nt] = __builtin_amdgcn_mfma_f32_16x16x32_bf16(ah[mt], bh, acc[mt][nt], 0, 0, 0);
                acc[mt][nt] = __builtin_amdgcn_mfma_f32_16x16x32_bf16(al[mt], bh, acc[mt][nt], 0, 0, 0);
                acc[mt][nt] = __builtin_amdgcn_mfma_f32_16x16x32_bf16(ah[mt], bl, acc[mt][nt], 0, 0, 0);
            }
        }
    }

    #pragma unroll
    for (int mt = 0; mt < 4; ++mt) {
        int mrow = bm + wm * 64 + mt * 16 + (lane >> 4) * 4;
        #pragma unroll
        for (int nt = 0; nt < 4; ++nt) {
            int n = bn + wn * 64 + nt * 16 + la;
            if (n < N) {
                float bi = bias ? bias[n] : 0.f;
                #pragma unroll
                for (int r = 0; r < 4; ++r)
                    C[(size_t)(mrow + r) * ldc + n + coff] = acc[mt][nt][r] + bi;
            }
        }
    }
}

// ---------------------------------------------------------------------------
// Grid barrier: per-block flag store, block-0 collects, release word.
// flags[NWG], release: zeroed before launch. gen is per-call monotonic.
// ---------------------------------------------------------------------------
__device__ inline void gridbar(int* flags, int* release, int& gen) {
    ++gen;
    __syncthreads();
    if (threadIdx.x == 0) {
        __builtin_amdgcn_fence(__ATOMIC_RELEASE, "agent");
        __hip_atomic_store(&flags[blockIdx.x], gen, __ATOMIC_RELAXED, __HIP_MEMORY_SCOPE_AGENT);
    }
    if (blockIdx.x == 0) {
        // 256 threads poll 256 flags in parallel
        while (__hip_atomic_load(&flags[threadIdx.x], __ATOMIC_RELAXED, __HIP_MEMORY_SCOPE_AGENT) < gen)
            __builtin_amdgcn_s_sleep(1);
        __syncthreads();
        if (threadIdx.x == 0)
            __hip_atomic_store(release, gen, __ATOMIC_RELAXED, __HIP_MEMORY_SCOPE_AGENT);
    } else if (threadIdx.x == 0) {
        while (__hip_atomic_load(release, __ATOMIC_RELAXED, __HIP_MEMORY_SCOPE_AGENT) < gen)
            __builtin_amdgcn_s_sleep(1);
    }
    __syncthreads();
    __builtin_amdgcn_fence(__ATOMIC_ACQUIRE, "agent");
}

// ---------------------------------------------------------------------------
// Persistent GRU layer: all 128 timesteps in one launch.
// NWG=256 blocks x 256 threads. Weight-stationary column partition:
//   phase A: 8 cols/block of [r|z] (2 cols/wave), phase B: 4 cols/block of h~
//   (waves 0,1 compute 2 cols each; all waves stage LDS).
// State hT [H][B]; Wx precomputed [T*B][3H].
// ---------------------------------------------------------------------------
__global__ __launch_bounds__(256, 1) void gru_layer(
    const float* __restrict__ Ur, const float* __restrict__ Uz,
    const float* __restrict__ Uh, const float* __restrict__ Wx,
    float* __restrict__ hT, float* __restrict__ rhT, float* __restrict__ zT,
    float* __restrict__ hseqT, int* flags, int* release)
{
    __shared__ float hs[KC * B];
    const int tid  = threadIdx.x;
    const int lane = tid & 63;
    const int wv   = __builtin_amdgcn_readfirstlane(tid >> 6);
    const int bid  = blockIdx.x;
    int gen = 0;

    const int jA = bid * 8;
    const float* __restrict__ UA = (jA < H) ? (Ur + (size_t)jA * H)
                                            : (Uz + (size_t)(jA - H) * H);
    const int ljA = wv * 2;
    const int jB = bid * 4;
    const int ljB = (wv & 1) * 2;   // used when wv < 2

    for (int t = 0; t < T; ++t) {
        // ---- phase A: r,z = sigmoid(Wx_rz + h @ [Ur;Uz]^T)
        {
            float acc0 = 0.f, acc1 = 0.f;
            for (int c = 0; c < H / KC; ++c) {
                __syncthreads();
                const float4* src = (const float4*)(hT + (size_t)c * KC * B);
                float4* dst = (float4*)hs;
                #pragma unroll
                for (int i = 0; i < (KC * B / 4) / 256; ++i)
                    dst[tid + i * 256] = src[tid + i * 256];
                __syncthreads();
                const float* __restrict__ u0 = UA + (size_t)(ljA + 0) * H + c * KC;
                const float* __restrict__ u1 = UA + (size_t)(ljA + 1) * H + c * KC;
                #pragma unroll 8
                for (int k = 0; k < KC; ++k) {
                    float hk = hs[k * B + lane];
                    acc0 = fmaf(hk, u0[k], acc0);
                    acc1 = fmaf(hk, u1[k], acc1);
                }
            }
            const size_t wxrow = ((size_t)t * B + lane) * (3 * H);
            float accv[2] = {acc0, acc1};
            #pragma unroll
            for (int jj = 0; jj < 2; ++jj) {
                int j = jA + ljA + jj;
                float val = accv[jj] + Wx[wxrow + j];
                float g = 1.f / (1.f + __expf(-val));
                if (j < H) rhT[(size_t)j * B + lane] = g * hT[(size_t)j * B + lane];
                else       zT[(size_t)(j - H) * B + lane] = g;
            }
        }
        gridbar(flags, release, gen);

        // ---- phase B: h~ = tanh(Wx_h + (r*h) @ Uh^T); h = (1-z)h + z h~
        {
            float acc0 = 0.f, acc1 = 0.f;
            for (int c = 0; c < H / KC; ++c) {
                __syncthreads();
                const float4* src = (const float4*)(rhT + (size_t)c * KC * B);
                float4* dst = (float4*)hs;
                #pragma unroll
                for (int i = 0; i < (KC * B / 4) / 256; ++i)
                    dst[tid + i * 256] = src[tid + i * 256];
                __syncthreads();
                if (wv < 2) {
                    const float* __restrict__ u0 = Uh + (size_t)(jB + ljB + 0) * H + c * KC;
                    const float* __restrict__ u1 = Uh + (size_t)(jB + ljB + 1) * H + c * KC;
                    #pragma unroll 8
                    for (int k = 0; k < KC; ++k) {
                        float hk = hs[k * B + lane];
                        acc0 = fmaf(hk, u0[k], acc0);
                        acc1 = fmaf(hk, u1[k], acc1);
                    }
                }
            }
            if (wv < 2) {
                const size_t wxrow = ((size_t)t * B + lane) * (3 * H) + 2 * H;
                float accv[2] = {acc0, acc1};
                #pragma unroll
                for (int jj = 0; jj < 2; ++jj) {
                    int j = jB + ljB + jj;
                    float val = accv[jj] + Wx[wxrow + j];
                    float htl = tanhf(val);
                    float z    = zT[(size_t)j * B + lane];
                    float hold = hT[(size_t)j * B + lane];
                    float hnew = (1.f - z) * hold + z * htl;
                    hT[(size_t)j * B + lane] = hnew;
                    hseqT[(size_t)t * H * B + (size_t)j * B + lane] = hnew;
                }
            }
        }
        gridbar(flags, release, gen);
    }
}

// ---------------------------------------------------------------------------
__global__ __launch_bounds__(256) void init_hT(
    const float* __restrict__ hidden, float* __restrict__ hT0, float* __restrict__ hT1)
{
    int idx = blockIdx.x * 256 + threadIdx.x;
    int l = idx / (B * H);
    int r = idx % (B * H);
    int b = r / H, k = r % H;
    float v = hidden[idx];
    float* dst = (l == 0) ? hT0 : hT1;
    dst[k * B + b] = v;
}

__global__ __launch_bounds__(256) void write_hfinal(
    const float* __restrict__ hT0, const float* __restrict__ hT1, float* __restrict__ outp)
{
    int idx = blockIdx.x * 256 + threadIdx.x;
    int l = idx / (B * H);
    int r = idx % (B * H);
    int b = r / H, k = r % H;
    const float* src = (l == 0) ? hT0 : hT1;
    outp[idx] = src[k * B + b];
}

// Transpose per-timestep: in [T][H][B] -> out [T*B][H]
__global__ __launch_bounds__(256) void transpose_TqB(
    const float* __restrict__ in, float* __restrict__ out)
{
    __shared__ float tile[64][65];
    const int t  = blockIdx.y;
    const int k0 = blockIdx.x * 64;
    const int tx = threadIdx.x % 64, ty = threadIdx.x / 64;
    const float* src = in + (size_t)t * H * B + (size_t)k0 * B;
    #pragma unroll
    for (int r = 0; r < 16; ++r) {
        int k = r * 4 + ty;
        tile[k][tx] = src[(size_t)k * B + tx];
    }
    __syncthreads();
    float* dst = out + (size_t)t * B * H + k0;
    #pragma unroll
    for (int r = 0; r < 16; ++r) {
        int b = r * 4 + ty;
        dst[(size_t)b * H + tx] = tile[tx][b];
    }
}

// ---------------------------------------------------------------------------
extern "C" void kernel_launch(void* const* d_in, const int* in_sizes, int n_in,
                              void* d_out, int out_size, void* d_ws, size_t ws_size,
                              hipStream_t stream)
{
    const int*   tok    = (const int*)d_in[0];
    const float* hidden = (const float*)d_in[1];
    const float* emb    = (const float*)d_in[2];
    const float* Wr0 = (const float*)d_in[3],  *br0 = (const float*)d_in[4];
    const float* Wz0 = (const float*)d_in[5],  *bz0 = (const float*)d_in[6];
    const float* Wh0 = (const float*)d_in[7],  *bh0 = (const float*)d_in[8];
    const float* Ur0 = (const float*)d_in[9],  *Uz0 = (const float*)d_in[10], *Uh0 = (const float*)d_in[11];
    const float* Wr1 = (const float*)d_in[12], *br1 = (const float*)d_in[13];
    const float* Wz1 = (const float*)d_in[14], *bz1 = (const float*)d_in[15];
    const float* Wh1 = (const float*)d_in[16], *bh1 = (const float*)d_in[17];
    const float* Ur1 = (const float*)d_in[18], *Uz1 = (const float*)d_in[19], *Uh1 = (const float*)d_in[20];
    const float* Wout = (const float*)d_in[21], *bout = (const float*)d_in[22];
    float* out = (float*)d_out;

    float* ws   = (float*)d_ws;
    float* Wx   = ws;                                  // T*B*3H
    float* bufT = Wx   + (size_t)T * B * 3 * H;        // T*H*B (hseq transposed)
    float* bufS = bufT + (size_t)T * H * B;            // T*B*H (hseq row-major)
    float* hT0  = bufS + (size_t)T * B * H;
    float* hT1  = hT0 + B * H;
    float* rhT  = hT1 + B * H;
    float* zTb  = rhT + B * H;
    int*   bar  = (int*)(zTb + B * H);                 // fl0[256] fl1[256] rel0 rel1
    int*   fl0  = bar;
    int*   fl1  = bar + NWG;
    int*   rel0 = bar + 2 * NWG;
    int*   rel1 = bar + 2 * NWG + 1;

    hipMemsetAsync(bar, 0, (2 * NWG + 2) * sizeof(int), stream);
    init_hT<<<(2 * B * H) / 256, 256, 0, stream>>>(hidden, hT0, hT1);

    // ---- layer 0: Wx = emb[tok] @ [Wr;Wz;Wh]^T + b  (gather fused)
    gemm_mfma_split<<<dim3(H / 128, T * B / 128), 256, 0, stream>>>(emb, Wr0, br0, Wx, tok, T * B, H, E, E, E, 3 * H, 0);
    gemm_mfma_split<<<dim3(H / 128, T * B / 128), 256, 0, stream>>>(emb, Wz0, bz0, Wx, tok, T * B, H, E, E, E, 3 * H, H);
    gemm_mfma_split<<<dim3(H / 128, T * B / 128), 256, 0, stream>>>(emb, Wh0, bh0, Wx, tok, T * B, H, E, E, E, 3 * H, 2 * H);

    gru_layer<<<NWG, 256, 0, stream>>>(Ur0, Uz0, Uh0, Wx, hT0, rhT, zTb, bufT, fl0, rel0);
    transpose_TqB<<<dim3(H / 64, T), 256, 0, stream>>>(bufT, bufS);

    // ---- layer 1: Wx = hseq0 @ [Wr1;Wz1;Wh1]^T + b
    gemm_mfma_split<<<dim3(H / 128, T * B / 128), 256, 0, stream>>>(bufS, Wr1, br1, Wx, nullptr, T * B, H, H, H, H, 3 * H, 0);
    gemm_mfma_split<<<dim3(H / 128, T * B / 128), 256, 0, stream>>>(bufS, Wz1, bz1, Wx, nullptr, T * B, H, H, H, H, 3 * H, H);
    gemm_mfma_split<<<dim3(H / 128, T * B / 128), 256, 0, stream>>>(bufS, Wh1, bh1, Wx, nullptr, T * B, H, H, H, H, 3 * H, 2 * H);

    gru_layer<<<NWG, 256, 0, stream>>>(Ur1, Uz1, Uh1, Wx, hT1, rhT, zTb, bufT, fl1, rel1);
    transpose_TqB<<<dim3(H / 64, T), 256, 0, stream>>>(bufT, bufS);

    // ---- logits = hseq1 @ Wout^T + bout
    gemm_mfma_split<<<dim3((V + 127) / 128, T * B / 128), 256, 0, stream>>>(bufS, Wout, bout, out, nullptr, T * B, V, H, H, H, V, 0);

    // ---- h_final
    write_hfinal<<<(2 * B * H) / 256, 256, 0, stream>>>(hT0, hT1, out + (size_t)T * B * V);
}

// Round 4
// 12372.100 us; speedup vs baseline: 1.6162x; 1.6162x over previous
//
#include <hip/hip_runtime.h>
#include <hip/hip_bf16.h>
#include <math.h>

#define V 10000
#define E 512
#define H 1024
#define T 128
#define B 64
#define NWG 256
#define KC 256   // k-chunk staged in LDS for persistent kernel (64 KB, proven resident)

typedef __bf16 bf16x8 __attribute__((ext_vector_type(8)));
typedef float f32x4 __attribute__((ext_vector_type(4)));
typedef unsigned short ushort8 __attribute__((ext_vector_type(8)));

// ---------------------------------------------------------------------------
// Cache-bypassing (coherent-at-MALL) scalar access helpers. sc0 sc1 = bypass
// L1 and L2, so stores are visible device-wide once vmcnt drains, and loads
// always observe the MALL-fresh value. No fences / L2 invalidations needed.
// ---------------------------------------------------------------------------
__device__ __forceinline__ void store_f32_sc(float* p, float v) {
    asm volatile("global_store_dword %0, %1, off sc0 sc1" :: "v"(p), "v"(v) : "memory");
}
__device__ __forceinline__ float load_f32_sc(const float* p) {
    float r;
    asm volatile("global_load_dword %0, %1, off sc0 sc1\n\ts_waitcnt vmcnt(0)"
                 : "=v"(r) : "v"(p) : "memory");
    return r;
}
__device__ __forceinline__ int load_i32_sc(const int* p) {
    int r;
    asm volatile("global_load_dword %0, %1, off sc0 sc1\n\ts_waitcnt vmcnt(0)"
                 : "=v"(r) : "v"(p) : "memory");
    return r;
}

// ---------------------------------------------------------------------------
// Fence-free grid barrier: 8 striped counters (one per 32 blocks, 128B apart).
// Pre-barrier: drain own stores (vmcnt) + syncthreads; arrive via relaxed
// agent atomicAdd; threads 0-7 poll the 8 counters with uncached loads.
// ---------------------------------------------------------------------------
__device__ __forceinline__ void gridbar(int* cnt, int gen) {
    asm volatile("s_waitcnt vmcnt(0)" ::: "memory");
    __syncthreads();
    if (threadIdx.x == 0)
        __hip_atomic_fetch_add(cnt + (blockIdx.x & 7) * 32, 1,
                               __ATOMIC_RELAXED, __HIP_MEMORY_SCOPE_AGENT);
    if (threadIdx.x < 8) {
        const int target = gen * (NWG / 8);
        while (load_i32_sc(cnt + threadIdx.x * 32) < target)
            __builtin_amdgcn_s_sleep(2);
    }
    __syncthreads();
}

// ---------------------------------------------------------------------------
// Split-pack 4 fp32 into truncated-hi bf16 and residual-lo bf16.
// ---------------------------------------------------------------------------
__device__ inline void splitpack(float4 v, uint2& hi, uint2& lo) {
    unsigned u0 = __float_as_uint(v.x), u1 = __float_as_uint(v.y);
    unsigned u2 = __float_as_uint(v.z), u3 = __float_as_uint(v.w);
    hi.x = __builtin_amdgcn_perm(u1, u0, 0x07060302u);
    hi.y = __builtin_amdgcn_perm(u3, u2, 0x07060302u);
    float l0 = v.x - __uint_as_float(u0 & 0xFFFF0000u);
    float l1 = v.y - __uint_as_float(u1 & 0xFFFF0000u);
    float l2 = v.z - __uint_as_float(u2 & 0xFFFF0000u);
    float l3 = v.w - __uint_as_float(u3 & 0xFFFF0000u);
    lo.x = __builtin_amdgcn_perm(__float_as_uint(l1), __float_as_uint(l0), 0x07060302u);
    lo.y = __builtin_amdgcn_perm(__float_as_uint(l3), __float_as_uint(l2), 0x07060302u);
}

// ---------------------------------------------------------------------------
// Split-bf16 MFMA GEMM (unchanged from round 2)
// ---------------------------------------------------------------------------
__global__ __launch_bounds__(256) void gemm_mfma_split(
    const float* __restrict__ A, const float* __restrict__ W,
    const float* __restrict__ bias, float* __restrict__ C,
    const int* __restrict__ rowidx,
    int M, int N, int K, int lda, int ldb, int ldc, int coff)
{
    __shared__ __align__(16) unsigned short Ah[128 * 40];
    __shared__ __align__(16) unsigned short Al[128 * 40];
    __shared__ __align__(16) unsigned short Bh[128 * 40];
    __shared__ __align__(16) unsigned short Bl[128 * 40];

    const int tid  = threadIdx.x;
    const int lane = tid & 63;
    const int wv   = tid >> 6;
    const int wm   = wv & 1, wn = wv >> 1;
    const int bn = blockIdx.x * 128;
    const int bm = blockIdx.y * 128;

    const float* apt[4];
    const float* bpt[4];
    bool bok[4];
    unsigned lofs[4];
    #pragma unroll
    for (int i = 0; i < 4; ++i) {
        int f4 = i * 256 + tid, r = f4 >> 3, kq = f4 & 7;
        int gm = bm + r;
        int ar = rowidx ? rowidx[gm] : gm;
        apt[i] = A + (size_t)ar * lda + kq * 4;
        int gn = bn + r;
        bok[i] = (gn < N);
        bpt[i] = W + (size_t)(bok[i] ? gn : 0) * ldb + kq * 4;
        lofs[i] = r * 40 + kq * 4;
    }

    f32x4 acc[4][4];
    #pragma unroll
    for (int i = 0; i < 4; ++i)
        #pragma unroll
        for (int j = 0; j < 4; ++j) acc[i][j] = (f32x4){0.f, 0.f, 0.f, 0.f};

    const int la  = lane & 15;
    const int kg8 = (lane >> 4) * 8;

    for (int k0 = 0; k0 < K; k0 += 32) {
        __syncthreads();
        #pragma unroll
        for (int i = 0; i < 4; ++i) {
            float4 va = *(const float4*)(apt[i] + k0);
            uint2 h, l;
            splitpack(va, h, l);
            *(uint2*)&Ah[lofs[i]] = h;
            *(uint2*)&Al[lofs[i]] = l;
            float4 vb = {0.f, 0.f, 0.f, 0.f};
            if (bok[i]) vb = *(const float4*)(bpt[i] + k0);
            splitpack(vb, h, l);
            *(uint2*)&Bh[lofs[i]] = h;
            *(uint2*)&Bl[lofs[i]] = l;
        }
        __syncthreads();

        bf16x8 ah[4], al[4];
        #pragma unroll
        for (int mt = 0; mt < 4; ++mt) {
            int row = (wm * 64 + mt * 16 + la) * 40 + kg8;
            ah[mt] = __builtin_bit_cast(bf16x8, *(const ushort8*)&Ah[row]);
            al[mt] = __builtin_bit_cast(bf16x8, *(const ushort8*)&Al[row]);
        }
        #pragma unroll
        for (int nt = 0; nt < 4; ++nt) {
            int row = (wn * 64 + nt * 16 + la) * 40 + kg8;
            bf16x8 bh = __builtin_bit_cast(bf16x8, *(const ushort8*)&Bh[row]);
            bf16x8 bl = __builtin_bit_cast(bf16x8, *(const ushort8*)&Bl[row]);
            #pragma unroll
            for (int mt = 0; mt < 4; ++mt) {
                acc[mt][nt] = __builtin_amdgcn_mfma_f32_16x16x32_bf16(ah[mt], bh, acc[mt][nt], 0, 0, 0);
                acc[mt][nt] = __builtin_amdgcn_mfma_f32_16x16x32_bf16(al[mt], bh, acc[mt][nt], 0, 0, 0);
                acc[mt][nt] = __builtin_amdgcn_mfma_f32_16x16x32_bf16(ah[mt], bl, acc[mt][nt], 0, 0, 0);
            }
        }
    }

    #pragma unroll
    for (int mt = 0; mt < 4; ++mt) {
        int mrow = bm + wm * 64 + mt * 16 + (lane >> 4) * 4;
        #pragma unroll
        for (int nt = 0; nt < 4; ++nt) {
            int n = bn + wn * 64 + nt * 16 + la;
            if (n < N) {
                float bi = bias ? bias[n] : 0.f;
                #pragma unroll
                for (int r = 0; r < 4; ++r)
                    C[(size_t)(mrow + r) * ldc + n + coff] = acc[mt][nt][r] + bi;
            }
        }
    }
}

// ---------------------------------------------------------------------------
// init: hidden [L][B][H] -> hinit_l [H][B] (transposed)
// ---------------------------------------------------------------------------
__global__ __launch_bounds__(256) void init_hT(
    const float* __restrict__ hidden, float* __restrict__ h0, float* __restrict__ h1)
{
    int idx = blockIdx.x * 256 + threadIdx.x;
    int l = idx / (B * H);
    int r = idx % (B * H);
    int b = r / H, k = r % H;
    float v = hidden[idx];
    float* dst = (l == 0) ? h0 : h1;
    dst[k * B + b] = v;
}

// ---------------------------------------------------------------------------
// Persistent GRU layer, fence-free. NWG=256 blocks x 256 threads.
// hseq: [T][H][B] rotating (slot t = h after step t); producers store sc0sc1,
// consumers read normally at fresh addresses. rh: [T][H][B] same protocol.
// zb: [H][B], consumed via uncached loads. hRM: [T*B][H] row-major for GEMMs.
// hfin: final-h destination ([B][H] slice of d_out).
// ---------------------------------------------------------------------------
__global__ __launch_bounds__(256, 1) void gru_layer(
    const float* __restrict__ Ur, const float* __restrict__ Uz,
    const float* __restrict__ Uh, const float* __restrict__ Wx,
    const float* __restrict__ hinit,
    float* __restrict__ hseq, float* __restrict__ rh, float* __restrict__ zb,
    float* __restrict__ hRM, float* __restrict__ hfin, int* cnt)
{
    __shared__ float hs[KC * B];
    const int tid  = threadIdx.x;
    const int lane = tid & 63;
    const int wv   = __builtin_amdgcn_readfirstlane(tid >> 6);
    const int bid  = blockIdx.x;
    int gen = 0;

    const int colA = bid * 8 + wv * 2;            // [0, 2048): r-cols then z-cols
    const float* __restrict__ UA = (bid < 128)
        ? (Ur + (size_t)colA * H)
        : (Uz + (size_t)(colA - H) * H);
    const int jB = bid * 4 + wv;                  // [0, 1024)
    const float* __restrict__ UB = Uh + (size_t)jB * H;

    for (int t = 0; t < T; ++t) {
        const float* __restrict__ hsrc = (t == 0) ? hinit : (hseq + (size_t)(t - 1) * H * B);

        // ---- phase A: r,z = sigmoid(Wx_rz + h @ [Ur;Uz]^T) ----
        {
            float a0 = 0.f, a1 = 0.f;
            for (int c = 0; c < H / KC; ++c) {
                __syncthreads();
                const float4* src = (const float4*)(hsrc + (size_t)c * KC * B);
                float4* dst = (float4*)hs;
                #pragma unroll
                for (int i = 0; i < (KC * B / 4) / 256; ++i)
                    dst[tid + i * 256] = src[tid + i * 256];
                __syncthreads();
                const float* __restrict__ u0 = UA + c * KC;
                const float* __restrict__ u1 = UA + H + c * KC;
                #pragma unroll 8
                for (int k = 0; k < KC; ++k) {
                    float hk = hs[k * B + lane];
                    a0 = fmaf(hk, u0[k], a0);
                    a1 = fmaf(hk, u1[k], a1);
                }
            }
            const float* wxr = Wx + ((size_t)t * B + lane) * (3 * H) + colA;
            float v0 = a0 + wxr[0], v1 = a1 + wxr[1];
            float g0 = 1.f / (1.f + __expf(-v0));
            float g1 = 1.f / (1.f + __expf(-v1));
            if (bid < 128) {
                float h0 = hsrc[(size_t)(colA + 0) * B + lane];
                float h1 = hsrc[(size_t)(colA + 1) * B + lane];
                store_f32_sc(rh + (size_t)t * H * B + (size_t)(colA + 0) * B + lane, g0 * h0);
                store_f32_sc(rh + (size_t)t * H * B + (size_t)(colA + 1) * B + lane, g1 * h1);
            } else {
                store_f32_sc(zb + (size_t)(colA - H + 0) * B + lane, g0);
                store_f32_sc(zb + (size_t)(colA - H + 1) * B + lane, g1);
            }
        }
        gridbar(cnt, ++gen);

        // ---- phase B: h~ = tanh(Wx_h + (r*h) @ Uh^T); h = (1-z)h + z h~ ----
        {
            float b0 = 0.f;
            const float* __restrict__ rsrc = rh + (size_t)t * H * B;
            for (int c = 0; c < H / KC; ++c) {
                __syncthreads();
                const float4* src = (const float4*)(rsrc + (size_t)c * KC * B);
                float4* dst = (float4*)hs;
                #pragma unroll
                for (int i = 0; i < (KC * B / 4) / 256; ++i)
                    dst[tid + i * 256] = src[tid + i * 256];
                __syncthreads();
                const float* __restrict__ u0 = UB + c * KC;
                #pragma unroll 8
                for (int k = 0; k < KC; ++k) {
                    float hk = hs[k * B + lane];
                    b0 = fmaf(hk, u0[k], b0);
                }
            }
            float v = b0 + Wx[((size_t)t * B + lane) * (3 * H) + 2 * H + jB];
            float htl = tanhf(v);
            float zv   = load_f32_sc(zb + (size_t)jB * B + lane);
            float hold = hsrc[(size_t)jB * B + lane];
            float hnew = (1.f - zv) * hold + zv * htl;
            store_f32_sc(hseq + (size_t)t * H * B + (size_t)jB * B + lane, hnew);
            store_f32_sc(hRM + ((size_t)t * B + lane) * H + jB, hnew);
            if (t == T - 1)
                store_f32_sc(hfin + (size_t)lane * H + jB, hnew);
        }
        gridbar(cnt, ++gen);
    }
}

// ---------------------------------------------------------------------------
extern "C" void kernel_launch(void* const* d_in, const int* in_sizes, int n_in,
                              void* d_out, int out_size, void* d_ws, size_t ws_size,
                              hipStream_t stream)
{
    const int*   tok    = (const int*)d_in[0];
    const float* hidden = (const float*)d_in[1];
    const float* emb    = (const float*)d_in[2];
    const float* Wr0 = (const float*)d_in[3],  *br0 = (const float*)d_in[4];
    const float* Wz0 = (const float*)d_in[5],  *bz0 = (const float*)d_in[6];
    const float* Wh0 = (const float*)d_in[7],  *bh0 = (const float*)d_in[8];
    const float* Ur0 = (const float*)d_in[9],  *Uz0 = (const float*)d_in[10], *Uh0 = (const float*)d_in[11];
    const float* Wr1 = (const float*)d_in[12], *br1 = (const float*)d_in[13];
    const float* Wz1 = (const float*)d_in[14], *bz1 = (const float*)d_in[15];
    const float* Wh1 = (const float*)d_in[16], *bh1 = (const float*)d_in[17];
    const float* Ur1 = (const float*)d_in[18], *Uz1 = (const float*)d_in[19], *Uh1 = (const float*)d_in[20];
    const float* Wout = (const float*)d_in[21], *bout = (const float*)d_in[22];
    float* out = (float*)d_out;

    float* ws    = (float*)d_ws;
    float* Wx    = ws;                                   // T*B*3H   = 25,165,824 f
    float* bufS  = Wx   + (size_t)T * B * 3 * H;         // T*B*H    =  8,388,608 f (row-major h)
    float* hseq  = bufS + (size_t)T * B * H;             // T*H*B    =  8,388,608 f (rotating)
    float* rhb   = hseq + (size_t)T * H * B;             // T*H*B    =  8,388,608 f (rotating)
    float* zb    = rhb  + (size_t)T * H * B;             // H*B
    float* hin0  = zb   + (size_t)H * B;                 // H*B
    float* hin1  = hin0 + (size_t)H * B;                 // H*B
    int*   cnt0  = (int*)(hin1 + (size_t)H * B);         // 8 counters * 32 ints
    int*   cnt1  = cnt0 + 8 * 32;

    hipMemsetAsync(cnt0, 0, 2 * 8 * 32 * sizeof(int), stream);
    init_hT<<<(2 * B * H) / 256, 256, 0, stream>>>(hidden, hin0, hin1);

    // ---- layer 0: Wx = emb[tok] @ [Wr;Wz;Wh]^T + b  (gather fused)
    gemm_mfma_split<<<dim3(H / 128, T * B / 128), 256, 0, stream>>>(emb, Wr0, br0, Wx, tok, T * B, H, E, E, E, 3 * H, 0);
    gemm_mfma_split<<<dim3(H / 128, T * B / 128), 256, 0, stream>>>(emb, Wz0, bz0, Wx, tok, T * B, H, E, E, E, 3 * H, H);
    gemm_mfma_split<<<dim3(H / 128, T * B / 128), 256, 0, stream>>>(emb, Wh0, bh0, Wx, tok, T * B, H, E, E, E, 3 * H, 2 * H);

    gru_layer<<<NWG, 256, 0, stream>>>(Ur0, Uz0, Uh0, Wx, hin0, hseq, rhb, zb,
                                       bufS, out + (size_t)T * B * V, cnt0);

    // ---- layer 1: Wx = hseq0_rowmajor @ [Wr1;Wz1;Wh1]^T + b
    gemm_mfma_split<<<dim3(H / 128, T * B / 128), 256, 0, stream>>>(bufS, Wr1, br1, Wx, nullptr, T * B, H, H, H, H, 3 * H, 0);
    gemm_mfma_split<<<dim3(H / 128, T * B / 128), 256, 0, stream>>>(bufS, Wz1, bz1, Wx, nullptr, T * B, H, H, H, H, 3 * H, H);
    gemm_mfma_split<<<dim3(H / 128, T * B / 128), 256, 0, stream>>>(bufS, Wh1, bh1, Wx, nullptr, T * B, H, H, H, H, 3 * H, 2 * H);

    gru_layer<<<NWG, 256, 0, stream>>>(Ur1, Uz1, Uh1, Wx, hin1, hseq, rhb, zb,
                                       bufS, out + (size_t)T * B * V + (size_t)B * H, cnt1);

    // ---- logits = hseq1_rowmajor @ Wout^T + bout
    gemm_mfma_split<<<dim3((V + 127) / 128, T * B / 128), 256, 0, stream>>>(bufS, Wout, bout, out, nullptr, T * B, V, H, H, H, V, 0);
}

// Round 5
// 5853.319 us; speedup vs baseline: 3.4162x; 2.1137x over previous
//
#include <hip/hip_runtime.h>
#include <hip/hip_bf16.h>
#include <math.h>

#define V 10000
#define E 512
#define H 1024
#define T 128
#define B 64
#define NWG 256
#define LDK 1032   // padded row stride (ushorts) for 16-row LDS tiles

typedef __bf16 bf16x8 __attribute__((ext_vector_type(8)));
typedef float f32x4 __attribute__((ext_vector_type(4)));
typedef unsigned short ushort8 __attribute__((ext_vector_type(8)));

// ---------------------------------------------------------------------------
// Cache-bypassing (coherent-at-MALL) access helpers.
// ---------------------------------------------------------------------------
__device__ __forceinline__ void store_f32_sc(float* p, float v) {
    asm volatile("global_store_dword %0, %1, off sc0 sc1" :: "v"(p), "v"(v) : "memory");
}
__device__ __forceinline__ int load_i32_sc(const int* p) {
    int r;
    asm volatile("global_load_dword %0, %1, off sc0 sc1\n\ts_waitcnt vmcnt(0)"
                 : "=v"(r) : "v"(p) : "memory");
    return r;
}

// ---------------------------------------------------------------------------
// Fence-free grid barrier (validated round 4): 8 striped counters.
// ---------------------------------------------------------------------------
__device__ __forceinline__ void gridbar(int* cnt, int gen) {
    asm volatile("s_waitcnt vmcnt(0)" ::: "memory");
    __syncthreads();
    if (threadIdx.x == 0)
        __hip_atomic_fetch_add(cnt + (blockIdx.x & 7) * 32, 1,
                               __ATOMIC_RELAXED, __HIP_MEMORY_SCOPE_AGENT);
    if (threadIdx.x < 8) {
        const int target = gen * (NWG / 8);
        while (load_i32_sc(cnt + threadIdx.x * 32) < target)
            __builtin_amdgcn_s_sleep(2);
    }
    __syncthreads();
}

// ---------------------------------------------------------------------------
// Split-pack 4 fp32 into truncated-hi bf16 and residual-lo bf16 (packed).
// ---------------------------------------------------------------------------
__device__ inline void splitpack(float4 v, uint2& hi, uint2& lo) {
    unsigned u0 = __float_as_uint(v.x), u1 = __float_as_uint(v.y);
    unsigned u2 = __float_as_uint(v.z), u3 = __float_as_uint(v.w);
    hi.x = __builtin_amdgcn_perm(u1, u0, 0x07060302u);
    hi.y = __builtin_amdgcn_perm(u3, u2, 0x07060302u);
    float l0 = v.x - __uint_as_float(u0 & 0xFFFF0000u);
    float l1 = v.y - __uint_as_float(u1 & 0xFFFF0000u);
    float l2 = v.z - __uint_as_float(u2 & 0xFFFF0000u);
    float l3 = v.w - __uint_as_float(u3 & 0xFFFF0000u);
    lo.x = __builtin_amdgcn_perm(__float_as_uint(l1), __float_as_uint(l0), 0x07060302u);
    lo.y = __builtin_amdgcn_perm(__float_as_uint(l3), __float_as_uint(l2), 0x07060302u);
}

// ---------------------------------------------------------------------------
// Split-bf16 MFMA GEMM (unchanged, proven rounds 2-4)
// ---------------------------------------------------------------------------
__global__ __launch_bounds__(256) void gemm_mfma_split(
    const float* __restrict__ A, const float* __restrict__ W,
    const float* __restrict__ bias, float* __restrict__ C,
    const int* __restrict__ rowidx,
    int M, int N, int K, int lda, int ldb, int ldc, int coff)
{
    __shared__ __align__(16) unsigned short Ah[128 * 40];
    __shared__ __align__(16) unsigned short Al[128 * 40];
    __shared__ __align__(16) unsigned short Bh[128 * 40];
    __shared__ __align__(16) unsigned short Bl[128 * 40];

    const int tid  = threadIdx.x;
    const int lane = tid & 63;
    const int wv   = tid >> 6;
    const int wm   = wv & 1, wn = wv >> 1;
    const int bn = blockIdx.x * 128;
    const int bm = blockIdx.y * 128;

    const float* apt[4];
    const float* bpt[4];
    bool bok[4];
    unsigned lofs[4];
    #pragma unroll
    for (int i = 0; i < 4; ++i) {
        int f4 = i * 256 + tid, r = f4 >> 3, kq = f4 & 7;
        int gm = bm + r;
        int ar = rowidx ? rowidx[gm] : gm;
        apt[i] = A + (size_t)ar * lda + kq * 4;
        int gn = bn + r;
        bok[i] = (gn < N);
        bpt[i] = W + (size_t)(bok[i] ? gn : 0) * ldb + kq * 4;
        lofs[i] = r * 40 + kq * 4;
    }

    f32x4 acc[4][4];
    #pragma unroll
    for (int i = 0; i < 4; ++i)
        #pragma unroll
        for (int j = 0; j < 4; ++j) acc[i][j] = (f32x4){0.f, 0.f, 0.f, 0.f};

    const int la  = lane & 15;
    const int kg8 = (lane >> 4) * 8;

    for (int k0 = 0; k0 < K; k0 += 32) {
        __syncthreads();
        #pragma unroll
        for (int i = 0; i < 4; ++i) {
            float4 va = *(const float4*)(apt[i] + k0);
            uint2 h, l;
            splitpack(va, h, l);
            *(uint2*)&Ah[lofs[i]] = h;
            *(uint2*)&Al[lofs[i]] = l;
            float4 vb = {0.f, 0.f, 0.f, 0.f};
            if (bok[i]) vb = *(const float4*)(bpt[i] + k0);
            splitpack(vb, h, l);
            *(uint2*)&Bh[lofs[i]] = h;
            *(uint2*)&Bl[lofs[i]] = l;
        }
        __syncthreads();

        bf16x8 ah[4], al[4];
        #pragma unroll
        for (int mt = 0; mt < 4; ++mt) {
            int row = (wm * 64 + mt * 16 + la) * 40 + kg8;
            ah[mt] = __builtin_bit_cast(bf16x8, *(const ushort8*)&Ah[row]);
            al[mt] = __builtin_bit_cast(bf16x8, *(const ushort8*)&Al[row]);
        }
        #pragma unroll
        for (int nt = 0; nt < 4; ++nt) {
            int row = (wn * 64 + nt * 16 + la) * 40 + kg8;
            bf16x8 bh = __builtin_bit_cast(bf16x8, *(const ushort8*)&Bh[row]);
            bf16x8 bl = __builtin_bit_cast(bf16x8, *(const ushort8*)&Bl[row]);
            #pragma unroll
            for (int mt = 0; mt < 4; ++mt) {
                acc[mt][nt] = __builtin_amdgcn_mfma_f32_16x16x32_bf16(ah[mt], bh, acc[mt][nt], 0, 0, 0);
                acc[mt][nt] = __builtin_amdgcn_mfma_f32_16x16x32_bf16(al[mt], bh, acc[mt][nt], 0, 0, 0);
                acc[mt][nt] = __builtin_amdgcn_mfma_f32_16x16x32_bf16(ah[mt], bl, acc[mt][nt], 0, 0, 0);
            }
        }
    }

    #pragma unroll
    for (int mt = 0; mt < 4; ++mt) {
        int mrow = bm + wm * 64 + mt * 16 + (lane >> 4) * 4;
        #pragma unroll
        for (int nt = 0; nt < 4; ++nt) {
            int n = bn + wn * 64 + nt * 16 + la;
            if (n < N) {
                float bi = bias ? bias[n] : 0.f;
                #pragma unroll
                for (int r = 0; r < 4; ++r)
                    C[(size_t)(mrow + r) * ldc + n + coff] = acc[mt][nt][r] + bi;
            }
        }
    }
}

// ---------------------------------------------------------------------------
// Prepass: split one fp32 matrix (n floats) into bf16 hi/lo.
// ---------------------------------------------------------------------------
__global__ __launch_bounds__(256) void split_mat(
    const float* __restrict__ U, unsigned short* __restrict__ hi,
    unsigned short* __restrict__ lo, int nf4)
{
    int idx = blockIdx.x * 256 + threadIdx.x;
    if (idx >= nf4) return;
    float4 v = ((const float4*)U)[idx];
    uint2 h, l;
    splitpack(v, h, l);
    ((uint2*)hi)[idx] = h;
    ((uint2*)lo)[idx] = l;
}

// ---------------------------------------------------------------------------
// Persistent MFMA GRU layer. 256 blocks x 256 threads (4 waves), 1 block/CU.
// Block = (m-tile of 16 batch rows, 16-col slice). XCD-aware mapping: the 4
// m-tile blocks sharing a col-slice land on one XCD (L2-resident U slice).
// Phase A: waves (gate r|z, k-half) -> r (to rhRM via sc stores), z (to LDS).
// Phase B: waves = 4 k-quarters of h~; wave 0 does the h update.
// All state row-major; cross-block data via sc0sc1 stores + fresh-address
// cached reads (validated round 4). U pre-split bf16 hi/lo (global, L2-hot).
// ---------------------------------------------------------------------------
__global__ __launch_bounds__(256, 1) void gru_layer(
    const unsigned short* __restrict__ Uhi, const unsigned short* __restrict__ Ulo,
    const float* __restrict__ Wx, const float* __restrict__ hprev0,
    float* __restrict__ hRM, float* __restrict__ rhRM,
    float* __restrict__ hfin, int* cnt)
{
    extern __shared__ char smem[];
    unsigned short* hA_hi = (unsigned short*)smem;              // 16*LDK
    unsigned short* hA_lo = hA_hi + 16 * LDK;
    unsigned short* rh_hi = hA_lo + 16 * LDK;
    unsigned short* rh_lo = rh_hi + 16 * LDK;
    float4* red4 = (float4*)(rh_lo + 16 * LDK);                 // 192 float4
    float*  zbuf = (float*)(red4 + 192);                        // 256 floats

    const int tid  = threadIdx.x;
    const int lane = tid & 63;
    const int wv   = __builtin_amdgcn_readfirstlane(tid >> 6);
    const int bid  = blockIdx.x;
    const int idx  = bid >> 3;
    const int nc   = (bid & 7) * 8 + (idx & 7);   // col-slice 0..63
    const int m0   = (idx >> 3) * 16;             // m-tile row base
    const int j0   = nc * 16;                     // col base
    const int la   = lane & 15;
    const int kg8  = (lane >> 4) * 8;
    const int srow = tid >> 4;                    // staging row 0..15
    const int skq  = tid & 15;
    const int erow = (lane >> 4) * 4;             // epilogue row group

    int gen = 0;
    const float* hprev = hprev0;

    for (int t = 0; t < T; ++t) {
        // ================= phase A: r and z =================
        {
            const int g  = wv >> 1;   // 0=r, 1=z
            const int kh = wv & 1;
            float wxp[4], hv[4];
            if (kh == 0) {
                #pragma unroll
                for (int q = 0; q < 4; ++q)
                    wxp[q] = Wx[((size_t)t * B + m0 + erow + q) * (3 * H) + g * H + j0 + la];
                if (g == 0) {
                    #pragma unroll
                    for (int q = 0; q < 4; ++q)
                        hv[q] = hprev[(size_t)(m0 + erow + q) * H + j0 + la];
                }
            }
            // stage h rows [m0, m0+16) -> LDS split
            {
                const float* src = hprev + (size_t)m0 * H;
                #pragma unroll
                for (int i = 0; i < 16; ++i) {
                    int k = i * 64 + skq * 4;
                    float4 v = *(const float4*)(src + (size_t)srow * H + k);
                    uint2 h2, l2;
                    splitpack(v, h2, l2);
                    *(uint2*)&hA_hi[srow * LDK + k] = h2;
                    *(uint2*)&hA_lo[srow * LDK + k] = l2;
                }
            }
            __syncthreads();
            f32x4 acc = (f32x4){0.f, 0.f, 0.f, 0.f};
            const unsigned short* ughi = Uhi + (size_t)g * H * H + (size_t)(j0 + la) * H + kh * 512 + kg8;
            const unsigned short* uglo = Ulo + (size_t)g * H * H + (size_t)(j0 + la) * H + kh * 512 + kg8;
            const int abase = la * LDK + kh * 512 + kg8;
            #pragma unroll
            for (int ks = 0; ks < 16; ++ks) {
                bf16x8 ah = __builtin_bit_cast(bf16x8, *(const ushort8*)&hA_hi[abase + ks * 32]);
                bf16x8 al = __builtin_bit_cast(bf16x8, *(const ushort8*)&hA_lo[abase + ks * 32]);
                bf16x8 bh = __builtin_bit_cast(bf16x8, *(const ushort8*)(ughi + ks * 32));
                bf16x8 bl = __builtin_bit_cast(bf16x8, *(const ushort8*)(uglo + ks * 32));
                acc = __builtin_amdgcn_mfma_f32_16x16x32_bf16(ah, bh, acc, 0, 0, 0);
                acc = __builtin_amdgcn_mfma_f32_16x16x32_bf16(al, bh, acc, 0, 0, 0);
                acc = __builtin_amdgcn_mfma_f32_16x16x32_bf16(ah, bl, acc, 0, 0, 0);
            }
            if (kh == 1)
                red4[g * 64 + lane] = (float4){acc[0], acc[1], acc[2], acc[3]};
            __syncthreads();
            if (kh == 0) {
                float4 p = red4[g * 64 + lane];
                acc[0] += p.x; acc[1] += p.y; acc[2] += p.z; acc[3] += p.w;
                if (g == 0) {
                    #pragma unroll
                    for (int q = 0; q < 4; ++q) {
                        float r = 1.f / (1.f + __expf(-(acc[q] + wxp[q])));
                        store_f32_sc(rhRM + ((size_t)t * B + m0 + erow + q) * H + j0 + la, r * hv[q]);
                    }
                } else {
                    #pragma unroll
                    for (int q = 0; q < 4; ++q)
                        zbuf[q * 64 + lane] = 1.f / (1.f + __expf(-(acc[q] + wxp[q])));
                }
            }
        }
        gridbar(cnt, ++gen);

        // ================= phase B: h~ and update =================
        {
            float wxp[4], hold[4];
            if (wv == 0) {
                #pragma unroll
                for (int q = 0; q < 4; ++q) {
                    wxp[q]  = Wx[((size_t)t * B + m0 + erow + q) * (3 * H) + 2 * H + j0 + la];
                    hold[q] = hprev[(size_t)(m0 + erow + q) * H + j0 + la];
                }
            }
            // stage rh rows -> LDS split
            {
                const float* src = rhRM + (size_t)t * B * H + (size_t)m0 * H;
                #pragma unroll
                for (int i = 0; i < 16; ++i) {
                    int k = i * 64 + skq * 4;
                    float4 v = *(const float4*)(src + (size_t)srow * H + k);
                    uint2 h2, l2;
                    splitpack(v, h2, l2);
                    *(uint2*)&rh_hi[srow * LDK + k] = h2;
                    *(uint2*)&rh_lo[srow * LDK + k] = l2;
                }
            }
            __syncthreads();
            f32x4 acc = (f32x4){0.f, 0.f, 0.f, 0.f};
            const unsigned short* ughi = Uhi + (size_t)2 * H * H + (size_t)(j0 + la) * H + wv * 256 + kg8;
            const unsigned short* uglo = Ulo + (size_t)2 * H * H + (size_t)(j0 + la) * H + wv * 256 + kg8;
            const int abase = la * LDK + wv * 256 + kg8;
            #pragma unroll
            for (int ks = 0; ks < 8; ++ks) {
                bf16x8 ah = __builtin_bit_cast(bf16x8, *(const ushort8*)&rh_hi[abase + ks * 32]);
                bf16x8 al = __builtin_bit_cast(bf16x8, *(const ushort8*)&rh_lo[abase + ks * 32]);
                bf16x8 bh = __builtin_bit_cast(bf16x8, *(const ushort8*)(ughi + ks * 32));
                bf16x8 bl = __builtin_bit_cast(bf16x8, *(const ushort8*)(uglo + ks * 32));
                acc = __builtin_amdgcn_mfma_f32_16x16x32_bf16(ah, bh, acc, 0, 0, 0);
                acc = __builtin_amdgcn_mfma_f32_16x16x32_bf16(al, bh, acc, 0, 0, 0);
                acc = __builtin_amdgcn_mfma_f32_16x16x32_bf16(ah, bl, acc, 0, 0, 0);
            }
            if (wv != 0)
                red4[(wv - 1) * 64 + lane] = (float4){acc[0], acc[1], acc[2], acc[3]};
            __syncthreads();
            if (wv == 0) {
                #pragma unroll
                for (int w = 0; w < 3; ++w) {
                    float4 p = red4[w * 64 + lane];
                    acc[0] += p.x; acc[1] += p.y; acc[2] += p.z; acc[3] += p.w;
                }
                #pragma unroll
                for (int q = 0; q < 4; ++q) {
                    float ht = tanhf(acc[q] + wxp[q]);
                    float z  = zbuf[q * 64 + lane];
                    float hnew = (1.f - z) * hold[q] + z * ht;
                    store_f32_sc(hRM + ((size_t)t * B + m0 + erow + q) * H + j0 + la, hnew);
                    if (t == T - 1)
                        store_f32_sc(hfin + (size_t)(m0 + erow + q) * H + j0 + la, hnew);
                }
            }
        }
        gridbar(cnt, ++gen);
        hprev = hRM + (size_t)t * B * H;
    }
}

// ---------------------------------------------------------------------------
extern "C" void kernel_launch(void* const* d_in, const int* in_sizes, int n_in,
                              void* d_out, int out_size, void* d_ws, size_t ws_size,
                              hipStream_t stream)
{
    const int*   tok    = (const int*)d_in[0];
    const float* hidden = (const float*)d_in[1];
    const float* emb    = (const float*)d_in[2];
    const float* Wr0 = (const float*)d_in[3],  *br0 = (const float*)d_in[4];
    const float* Wz0 = (const float*)d_in[5],  *bz0 = (const float*)d_in[6];
    const float* Wh0 = (const float*)d_in[7],  *bh0 = (const float*)d_in[8];
    const float* Ur0 = (const float*)d_in[9],  *Uz0 = (const float*)d_in[10], *Uh0 = (const float*)d_in[11];
    const float* Wr1 = (const float*)d_in[12], *br1 = (const float*)d_in[13];
    const float* Wz1 = (const float*)d_in[14], *bz1 = (const float*)d_in[15];
    const float* Wh1 = (const float*)d_in[16], *bh1 = (const float*)d_in[17];
    const float* Ur1 = (const float*)d_in[18], *Uz1 = (const float*)d_in[19], *Uh1 = (const float*)d_in[20];
    const float* Wout = (const float*)d_in[21], *bout = (const float*)d_in[22];
    float* out = (float*)d_out;

    float* ws   = (float*)d_ws;
    float* Wx   = ws;                                    // T*B*3H
    float* hRM  = Wx  + (size_t)T * B * 3 * H;           // T*B*H
    float* rhRM = hRM + (size_t)T * B * H;               // T*B*H
    unsigned short* Uhi = (unsigned short*)(rhRM + (size_t)T * B * H);  // 2*3*H*H
    unsigned short* Ulo = Uhi + (size_t)2 * 3 * H * H;
    int* cnt = (int*)(Ulo + (size_t)2 * 3 * H * H);      // 2 * 256 ints

    const size_t HH = (size_t)H * H;
    const int nf4 = (int)(HH / 4);

    static bool attr_set = false;
    if (!attr_set) {
        hipFuncSetAttribute((const void*)gru_layer,
                            hipFuncAttributeMaxDynamicSharedMemorySize, 136192);
        attr_set = true;
    }

    hipMemsetAsync(cnt, 0, 2 * 256 * sizeof(int), stream);

    // prepass: split all 6 U matrices to bf16 hi/lo
    split_mat<<<nf4 / 256, 256, 0, stream>>>(Ur0, Uhi + 0 * HH, Ulo + 0 * HH, nf4);
    split_mat<<<nf4 / 256, 256, 0, stream>>>(Uz0, Uhi + 1 * HH, Ulo + 1 * HH, nf4);
    split_mat<<<nf4 / 256, 256, 0, stream>>>(Uh0, Uhi + 2 * HH, Ulo + 2 * HH, nf4);
    split_mat<<<nf4 / 256, 256, 0, stream>>>(Ur1, Uhi + 3 * HH, Ulo + 3 * HH, nf4);
    split_mat<<<nf4 / 256, 256, 0, stream>>>(Uz1, Uhi + 4 * HH, Ulo + 4 * HH, nf4);
    split_mat<<<nf4 / 256, 256, 0, stream>>>(Uh1, Uhi + 5 * HH, Ulo + 5 * HH, nf4);

    // ---- layer 0: Wx = emb[tok] @ [Wr;Wz;Wh]^T + b  (gather fused)
    gemm_mfma_split<<<dim3(H / 128, T * B / 128), 256, 0, stream>>>(emb, Wr0, br0, Wx, tok, T * B, H, E, E, E, 3 * H, 0);
    gemm_mfma_split<<<dim3(H / 128, T * B / 128), 256, 0, stream>>>(emb, Wz0, bz0, Wx, tok, T * B, H, E, E, E, 3 * H, H);
    gemm_mfma_split<<<dim3(H / 128, T * B / 128), 256, 0, stream>>>(emb, Wh0, bh0, Wx, tok, T * B, H, E, E, E, 3 * H, 2 * H);

    gru_layer<<<NWG, 256, 136192, stream>>>(Uhi, Ulo, Wx, hidden,
                                            hRM, rhRM, out + (size_t)T * B * V, cnt);

    // ---- layer 1: Wx = h0_seq @ [Wr1;Wz1;Wh1]^T + b
    gemm_mfma_split<<<dim3(H / 128, T * B / 128), 256, 0, stream>>>(hRM, Wr1, br1, Wx, nullptr, T * B, H, H, H, H, 3 * H, 0);
    gemm_mfma_split<<<dim3(H / 128, T * B / 128), 256, 0, stream>>>(hRM, Wz1, bz1, Wx, nullptr, T * B, H, H, H, H, 3 * H, H);
    gemm_mfma_split<<<dim3(H / 128, T * B / 128), 256, 0, stream>>>(hRM, Wh1, bh1, Wx, nullptr, T * B, H, H, H, H, 3 * H, 2 * H);

    gru_layer<<<NWG, 256, 136192, stream>>>(Uhi + 3 * HH, Ulo + 3 * HH, Wx, hidden + (size_t)B * H,
                                            hRM, rhRM, out + (size_t)T * B * V + (size_t)B * H, cnt + 256);

    // ---- logits = h1_seq @ Wout^T + bout
    gemm_mfma_split<<<dim3((V + 127) / 128, T * B / 128), 256, 0, stream>>>(hRM, Wout, bout, out, nullptr, T * B, V, H, H, H, V, 0);
}